// Round 2
// baseline (146.553 us; speedup 1.0000x reference)
//
#include <hip/hip_runtime.h>
#include <hip/hip_bf16.h>
#include <stdint.h>

// Problem constants
#define BATCH 4096
#define NT    8192          // 2*BATCH
#define FD    256           // feature dim
#define TILE  128           // block tile (TILE x TILE of the pair matrix)
#define NBLK  64            // NT / TILE
#define NTRI  2080          // NBLK*(NBLK+1)/2 upper-triangle tiles
#define NUMK  5

typedef __attribute__((ext_vector_type(8))) short bf16x8;  // 8 bf16 = 4 VGPRs
typedef __attribute__((ext_vector_type(4))) float f32x4;

// ---- workspace layout (bytes) ----
static const size_t WS_FB    = 0;                           // bf16 feats [8192][256] = 4 MiB
static const size_t WS_SQ    = (size_t)NT * FD * 2;         // sq[8192] f32 (+32 KiB)
static const size_t WS_COLP  = WS_SQ + (size_t)NT * 4;      // colpart[256][256] f32 (+256 KiB)
static const size_t WS_SQP   = WS_COLP + 256 * 256 * 4;     // sqpart[256] f32 (+1 KiB)
static const size_t WS_CNT   = WS_SQP + 256 * 4;            // counter u32 (memset 0)
static const size_t WS_GAMMA = WS_CNT + 4;                  // gamma0 f32

__device__ __forceinline__ unsigned short f2bf_rne(float x) {
    unsigned u = __float_as_uint(x);
    unsigned r = (u + 0x7fffu + ((u >> 16) & 1u)) >> 16;
    return (unsigned short)r;
}

__device__ __forceinline__ void async_copy16(void* lds, const void* g) {
    __builtin_amdgcn_global_load_lds(
        (__attribute__((address_space(1))) void*)(void*)(const_cast<void*>(g)),
        (__attribute__((address_space(3))) void*)lds, 16, 0, 0);
}

// ------- kernel 1: convert + row norms + colsum partials + (last block) gamma -------
__global__ void mmd_prep(const float* __restrict__ s_feat,
                         const float* __restrict__ t_feat,
                         unsigned short* __restrict__ fb,
                         float* __restrict__ sq,
                         float* __restrict__ colpart,
                         float* __restrict__ sqpart,
                         unsigned int* __restrict__ counter,
                         float* __restrict__ gamma) {
    __shared__ float cp[4][FD];
    __shared__ float red[4];
    __shared__ bool last;
    const int w    = threadIdx.x >> 6;
    const int lane = threadIdx.x & 63;
    float c0 = 0.f, c1 = 0.f, c2 = 0.f, c3 = 0.f;
    float wtot = 0.f;
    for (int t = 0; t < 8; ++t) {
        int row = blockIdx.x * 32 + w * 8 + t;
        const float* src = (row < BATCH) ? (s_feat + (size_t)row * FD)
                                         : (t_feat + (size_t)(row - BATCH) * FD);
        float4 v = ((const float4*)src)[lane];
        unsigned int u01 = (unsigned)f2bf_rne(v.x) | ((unsigned)f2bf_rne(v.y) << 16);
        unsigned int u23 = (unsigned)f2bf_rne(v.z) | ((unsigned)f2bf_rne(v.w) << 16);
        ((uint2*)(fb + (size_t)row * FD))[lane] = make_uint2(u01, u23);
        float ss = v.x * v.x + v.y * v.y + v.z * v.z + v.w * v.w;
        for (int off = 32; off; off >>= 1) ss += __shfl_down(ss, off);
        if (lane == 0) { sq[row] = ss; wtot += ss; }
        c0 += v.x; c1 += v.y; c2 += v.z; c3 += v.w;
    }
    cp[w][4 * lane + 0] = c0;
    cp[w][4 * lane + 1] = c1;
    cp[w][4 * lane + 2] = c2;
    cp[w][4 * lane + 3] = c3;
    if (lane == 0) red[w] = wtot;
    __syncthreads();
    int t = threadIdx.x;
    colpart[blockIdx.x * 256 + t] = cp[0][t] + cp[1][t] + cp[2][t] + cp[3][t];
    if (t == 0) sqpart[blockIdx.x] = red[0] + red[1] + red[2] + red[3];
    __threadfence();
    __syncthreads();
    if (t == 0) {
        unsigned int old = atomicAdd(counter, 1u);
        last = (old == 255u);
    }
    __syncthreads();
    if (!last) return;
    __threadfence();
    // last block: reduce partials -> gamma
    float cs = 0.f;
    for (int b = 0; b < 256; ++b) cs += colpart[b * 256 + t];
    float v = cs * cs;
    float sp = sqpart[t];
    for (int off = 32; off; off >>= 1) {
        v  += __shfl_down(v, off);
        sp += __shfl_down(sp, off);
    }
    __syncthreads();   // reuse red[]
    if (lane == 0) { red[w] = v; cp[0][w] = sp; }
    __syncthreads();
    if (t == 0) {
        float s2    = red[0] + red[1] + red[2] + red[3];
        float sumsq = cp[0][0] + cp[0][1] + cp[0][2] + cp[0][3];
        // sum(distances) = 2*n*sum(sq) - 2*||colsum||^2  (diag clamp negligible)
        float sumd = 2.0f * (float)NT * sumsq - 2.0f * s2;
        float n2n  = (float)((long long)NT * NT - NT);
        gamma[0]   = 0.25f * (n2n / sumd);   // bandwidth / 2^(NUM_KERNELS//2)
    }
}

// ------- kernel 2: fused GEMM + gaussian mixture + reduce -------
// A tile staged once (full K) in LDS with XOR-chunk swizzle; B fragments read
// directly from global (L2-resident); no barriers in the compute loop.
__global__ __launch_bounds__(256) void mmd_main(
    const unsigned short* __restrict__ fb,
    const float* __restrict__ sq,
    const float* __restrict__ gamma,
    float* __restrict__ out) {
    // decode upper-triangle linear index -> (bi, bj), block-uniform scalar loop
    int t = blockIdx.x, bi = 0;
    while (t >= NBLK - bi) { t -= NBLK - bi; ++bi; }
    const int bj = bi + t;

    __shared__ __align__(16) unsigned short a_t[TILE * FD];  // 64 KiB, swizzled
    __shared__ float sqa[TILE], sqb[TILE];
    __shared__ float red[4];

    const int tid  = threadIdx.x;
    const int w    = tid >> 6, lane = tid & 63;
    const int wm   = w & 1, wn = w >> 1;          // 2x2 waves over 128x128
    const int quad = lane >> 4, m16 = lane & 15;

    const size_t rowA0 = (size_t)bi * TILE;
    const size_t rowB0 = (size_t)bj * TILE;

    // ---- stage A (full K) : 16 async 1-KiB wave-copies per wave, 2 rows each ----
    {
        const int r2 = lane >> 5;          // row within the 2-row pair
        const int p  = lane & 31;          // physical 16B-chunk slot (32 per row)
#pragma unroll
        for (int i = 0; i < 16; ++i) {
            int row = w * 32 + i * 2 + r2;
            int c   = p ^ (row & 7);       // slot p holds global chunk p^(row&7)
            async_copy16(&a_t[(w * 32 + i * 2) * FD],
                         fb + (rowA0 + row) * FD + c * 8);
        }
    }
    if (tid < TILE) sqa[tid] = sq[rowA0 + tid];
    else            sqb[tid - TILE] = sq[rowB0 + (tid - TILE)];

    // ---- B fragment pointers (direct global, per-lane) ----
    const unsigned short* bp[4];
#pragma unroll
    for (int tn = 0; tn < 4; ++tn)
        bp[tn] = fb + (rowB0 + wn * 64 + tn * 16 + m16) * FD + quad * 8;

    bf16x8 bcur[4], bnxt[4];
#pragma unroll
    for (int tn = 0; tn < 4; ++tn) bcur[tn] = *(const bf16x8*)bp[tn];  // kk=0

    const f32x4 fzero = {0.f, 0.f, 0.f, 0.f};
    f32x4 acc[4][4];
#pragma unroll
    for (int a = 0; a < 4; ++a)
#pragma unroll
        for (int b = 0; b < 4; ++b) acc[a][b] = fzero;

    __syncthreads();   // drains staging (vmcnt) + sqa/sqb; the ONLY gemm barrier

#pragma unroll
    for (int kk = 0; kk < 8; ++kk) {       // 8 x k32 steps
        if (kk < 7) {
#pragma unroll
            for (int tn = 0; tn < 4; ++tn)
                bnxt[tn] = *(const bf16x8*)(bp[tn] + (kk + 1) * 32);
        }
        bf16x8 af[4];
        const int cl = kk * 4 + quad;      // logical 16B chunk 0..31
#pragma unroll
        for (int tm = 0; tm < 4; ++tm) {
            int row = wm * 64 + tm * 16 + m16;
            int p = cl ^ (row & 7);
            af[tm] = *(const bf16x8*)&a_t[row * FD + p * 8];
        }
#pragma unroll
        for (int tm = 0; tm < 4; ++tm)
#pragma unroll
            for (int tn = 0; tn < 4; ++tn)
                acc[tm][tn] = __builtin_amdgcn_mfma_f32_16x16x32_bf16(
                    af[tm], bcur[tn], acc[tm][tn], 0, 0, 0);
        if (kk < 7) {
#pragma unroll
            for (int tn = 0; tn < 4; ++tn) bcur[tn] = bnxt[tn];
        }
    }

    // ---- epilogue: d = sq_i + sq_j - 2 dot, clamp, e + e^2 + e^4 + e^8 + e^16 ----
    const float g0 = gamma[0];
    float lsum = 0.f;
#pragma unroll
    for (int tm = 0; tm < 4; ++tm) {
        const int i0 = wm * 64 + tm * 16 + quad * 4;
        float sqi[4] = {sqa[i0 + 0], sqa[i0 + 1], sqa[i0 + 2], sqa[i0 + 3]};
#pragma unroll
        for (int tn = 0; tn < 4; ++tn) {
            const int j = wn * 64 + tn * 16 + m16;
            const float sqj = sqb[j];
#pragma unroll
            for (int r = 0; r < 4; ++r) {
                float d = fmaf(-2.f, acc[tm][tn][r], sqi[r] + sqj);
                d = fmaxf(d, 0.f);
                float e1 = __expf(-d * g0);
                float e2 = e1 * e1, e4 = e2 * e2, e8 = e4 * e4, e16 = e8 * e8;
                lsum += e1 + e2 + e4 + e8 + e16;
            }
        }
    }
    for (int off = 32; off; off >>= 1) lsum += __shfl_down(lsum, off);
    if (lane == 0) red[w] = lsum;
    __syncthreads();
    if (tid == 0) {
        float wgt;
        if (bi == bj) wgt = 1.f;                                  // diagonal tile
        else wgt = ((bi < NBLK / 2) == (bj < NBLK / 2)) ? 2.f : -2.f;
        float scale = wgt * (1.f / NUMK) * (1.f / 16777216.f);    // / (5 * 4096^2)
        atomicAdd(out, (red[0] + red[1] + red[2] + red[3]) * scale);
    }
}

extern "C" void kernel_launch(void* const* d_in, const int* in_sizes, int n_in,
                              void* d_out, int out_size, void* d_ws, size_t ws_size,
                              hipStream_t stream) {
    const float* s_feat = (const float*)d_in[0];
    const float* t_feat = (const float*)d_in[1];
    char* ws = (char*)d_ws;
    unsigned short* fb  = (unsigned short*)(ws + WS_FB);
    float* sq      = (float*)(ws + WS_SQ);
    float* colpart = (float*)(ws + WS_COLP);
    float* sqpart  = (float*)(ws + WS_SQP);
    unsigned int* counter = (unsigned int*)(ws + WS_CNT);
    float* gamma   = (float*)(ws + WS_GAMMA);
    float* out     = (float*)d_out;

    hipMemsetAsync(counter, 0, 4, stream);
    hipMemsetAsync(d_out, 0, sizeof(float), stream);

    mmd_prep<<<NT / 32, 256, 0, stream>>>(s_feat, t_feat, fb, sq,
                                          colpart, sqpart, counter, gamma);
    mmd_main<<<NTRI, 256, 0, stream>>>(fb, sq, gamma, out);
}